// Round 2
// baseline (162.671 us; speedup 1.0000x reference)
//
#include <hip/hip_runtime.h>

#define N_ 4
#define C_ 256
#define H_ 128
#define W_ 128
#define HW_ (H_*W_)
#define BINS 256      // 16x16 pooled positions
#define OC 9
#define EPS_ 1e-5f

// Kernel 1: 8x8 average pool, atomic-free. Block per (n,c), 256 threads,
// fully-coalesced float4 reads. Per k-iteration (one 8-row band):
//   wave w's lanes cover rows {8k+2w, 8k+2w+1}; lane l covers cols 4(l&31)..+3.
//   shfl_xor(1) -> 8-col bin sum per row; shfl_xor(32) -> both rows combined.
//   16 even low lanes/wave write per-wave partials to LDS (conflict-free).
// Output transposed: xpT[c][n*256+bin] so stage 2 reads coalesced.
__global__ __launch_bounds__(256) void pool_kernel(const float* __restrict__ x,
                                                   float* __restrict__ xpT) {
    int b = blockIdx.x;          // n*C + c
    int n = b >> 8, c = b & 255;
    const float4* xv = (const float4*)(x + (size_t)b * HW_);
    __shared__ float part[4 * 256];
    int t = threadIdx.x;
    int w = t >> 6, l = t & 63;
    int j = (l & 31) >> 1;       // col bin 0..15
    bool writer = (l < 32) && ((l & 1) == 0);
    #pragma unroll
    for (int k = 0; k < 16; ++k) {
        float4 v = xv[k * 256 + t];   // coalesced: flat pixel = k*1024 + 4t
        float s = v.x + v.y + v.z + v.w;
        s += __shfl_xor(s, 1);        // pair lanes -> 8 cols of one row
        s += __shfl_xor(s, 32);       // combine the wave's two rows
        if (writer) part[w * 256 + k * 16 + j] = s;
    }
    __syncthreads();
    float r = part[t] + part[256 + t] + part[512 + t] + part[768 + t];
    xpT[((size_t)c << 10) + (n << 8) + t] = r * (1.f / 64.f);
}

// Kernel 2: fused 1x1 conv + BatchNorm. Block per output channel o (9 blocks).
// Thread t owns samples {t, 256+t, 512+t, 768+t} (sample = n*256+bin).
// Inner loop over c: scalar weight broadcast (s_load), coalesced xpT reads.
// BN stats are block-local (all 1024 samples live in this block).
__global__ __launch_bounds__(256) void convbn_kernel(const float* __restrict__ xpT,
                                                     const float* __restrict__ wconv,
                                                     const float* __restrict__ gamma,
                                                     const float* __restrict__ beta,
                                                     float* __restrict__ w9) {
    int o = blockIdx.x;
    int t = threadIdx.x;
    const float* wrow = wconv + o * 256;
    float acc0 = 0.f, acc1 = 0.f, acc2 = 0.f, acc3 = 0.f;
    #pragma unroll 4
    for (int c = 0; c < 256; ++c) {
        float wv = wrow[c];
        const float* p = xpT + (c << 10) + t;
        acc0 += wv * p[0];
        acc1 += wv * p[256];
        acc2 += wv * p[512];
        acc3 += wv * p[768];
    }
    float sum = acc0 + acc1 + acc2 + acc3;
    float sq  = acc0*acc0 + acc1*acc1 + acc2*acc2 + acc3*acc3;
    #pragma unroll
    for (int off = 32; off > 0; off >>= 1) {
        sum += __shfl_down(sum, off);
        sq  += __shfl_down(sq, off);
    }
    __shared__ float ls[8];
    __shared__ float sc[2];
    int w = t >> 6;
    if ((t & 63) == 0) { ls[w] = sum; ls[4 + w] = sq; }
    __syncthreads();
    if (t == 0) {
        float S = ls[0] + ls[1] + ls[2] + ls[3];
        float Q = ls[4] + ls[5] + ls[6] + ls[7];
        float mu = S * (1.f / 1024.f);
        float var = Q * (1.f / 1024.f) - mu * mu;
        float scale = gamma[o] * rsqrtf(var + EPS_);
        sc[0] = scale;
        sc[1] = beta[o] - mu * scale;
    }
    __syncthreads();
    float scale = sc[0], shift = sc[1];
    w9[(0 * 256 + t) * 9 + o] = acc0 * scale + shift;
    w9[(1 * 256 + t) * 9 + o] = acc1 * scale + shift;
    w9[(2 * 256 + t) * 9 + o] = acc2 * scale + shift;
    w9[(3 * 256 + t) * 9 + o] = acc3 * scale + shift;
}

// Kernel 3: depthwise 3x3 conv, per-(n,ch) dynamic 9-tap kernel, zero pad 1.
// Block per (n,ch,row-tile of 16). LDS tile 18 rows x 132 (16B-aligned row
// stride; col x at index x+1; halo cols zeroed). 2-row x 4-col micro-tile.
__global__ __launch_bounds__(256) void dwconv_kernel(const float* __restrict__ x,
                                                     const float* __restrict__ w9,
                                                     float* __restrict__ out) {
    int b = blockIdx.x;
    int plane = b >> 3;          // n*C + ch
    int rt = b & 7;
    int r0 = rt * 16;
    const float* xin = x + (size_t)plane * HW_;
    float* po = out + (size_t)plane * HW_;
    const float* wp = w9 + plane * 9;    // block-uniform -> scalar loads
    float w[9];
    #pragma unroll
    for (int i = 0; i < 9; ++i) w[i] = wp[i];

    __shared__ __align__(16) float lds[18 * 132];
    int t = threadIdx.x;
    if (t < 18) {                 // zero halo columns (col -1 and col 128)
        lds[t * 132] = 0.f;
        lds[t * 132 + 129] = 0.f;
    }
    #pragma unroll
    for (int i = 0; i < 3; ++i) {
        int vi = i * 256 + t;
        if (vi < 576) {
            int lr = vi >> 5;            // lds row 0..17
            int c4 = (vi & 31) << 2;     // col 0,4,...,124
            int gr = r0 - 1 + lr;        // global row
            float4 val = make_float4(0.f, 0.f, 0.f, 0.f);
            if (gr >= 0 && gr < H_) val = *(const float4*)&xin[gr * W_ + c4];
            float* d = &lds[lr * 132 + c4 + 1];
            d[0] = val.x; d[1] = val.y; d[2] = val.z; d[3] = val.w;
        }
    }
    __syncthreads();

    int mr = t >> 5;              // 0..7  -> out rows olr, olr+1
    int mc = t & 31;              // 0..31 -> out cols mc*4..mc*4+3
    int olr = mr * 2;
    int oc0 = mc * 4;
    float rowv[4][6];
    #pragma unroll
    for (int j = 0; j < 4; ++j) {
        const float* rp = &lds[(olr + j) * 132 + oc0];
        float4 a = *(const float4*)rp;    // 16B-aligned ds_read_b128
        rowv[j][0] = a.x; rowv[j][1] = a.y; rowv[j][2] = a.z; rowv[j][3] = a.w;
        rowv[j][4] = rp[4]; rowv[j][5] = rp[5];
    }
    #pragma unroll
    for (int rr = 0; rr < 2; ++rr) {
        float res[4];
        #pragma unroll
        for (int cc = 0; cc < 4; ++cc) {
            float s = 0.f;
            #pragma unroll
            for (int dy = 0; dy < 3; ++dy)
                #pragma unroll
                for (int dx = 0; dx < 3; ++dx)
                    s += w[dy * 3 + dx] * rowv[rr + dy][cc + dx];
            res[cc] = s;
        }
        *(float4*)&po[(r0 + olr + rr) * W_ + oc0] =
            make_float4(res[0], res[1], res[2], res[3]);
    }
}

extern "C" void kernel_launch(void* const* d_in, const int* in_sizes, int n_in,
                              void* d_out, int out_size, void* d_ws, size_t ws_size,
                              hipStream_t stream) {
    const float* x     = (const float*)d_in[0];
    const float* wconv = (const float*)d_in[1];
    const float* gamma = (const float*)d_in[2];
    const float* beta  = (const float*)d_in[3];
    float* out = (float*)d_out;

    float* xpT = (float*)d_ws;                  // C * N*BINS = 262144 floats
    float* w9  = xpT + C_ * N_ * BINS;          // N*BINS*OC  = 9216 floats

    pool_kernel  <<<N_ * C_,     256, 0, stream>>>(x, xpT);
    convbn_kernel<<<OC,          256, 0, stream>>>(xpT, wconv, gamma, beta, w9);
    dwconv_kernel<<<N_ * C_ * 8, 256, 0, stream>>>(x, w9, out);
}

// Round 3
// 150.461 us; speedup vs baseline: 1.0812x; 1.0812x over previous
//
#include <hip/hip_runtime.h>

#define N_ 4
#define C_ 256
#define H_ 128
#define W_ 128
#define HW_ (H_*W_)
#define BINS 256      // 16x16 pooled positions
#define OC 9
#define EPS_ 1e-5f

// Kernel 1: 8x8 average pool, atomic-free. Block per (n,c), 256 threads,
// fully-coalesced float4 reads. shfl_xor collapses each wave's partials;
// output transposed: xpT[c][n*256+bin] so stage 2 reads coalesced.
__global__ __launch_bounds__(256) void pool_kernel(const float* __restrict__ x,
                                                   float* __restrict__ xpT) {
    int b = blockIdx.x;          // n*C + c
    int n = b >> 8, c = b & 255;
    const float4* xv = (const float4*)(x + (size_t)b * HW_);
    __shared__ float part[4 * 256];
    int t = threadIdx.x;
    int w = t >> 6, l = t & 63;
    int j = (l & 31) >> 1;       // col bin 0..15
    bool writer = (l < 32) && ((l & 1) == 0);
    #pragma unroll
    for (int k = 0; k < 16; ++k) {
        float4 v = xv[k * 256 + t];   // coalesced: flat pixel = k*1024 + 4t
        float s = v.x + v.y + v.z + v.w;
        s += __shfl_xor(s, 1);        // pair lanes -> 8 cols of one row
        s += __shfl_xor(s, 32);       // combine the wave's two rows
        if (writer) part[w * 256 + k * 16 + j] = s;
    }
    __syncthreads();
    float r = part[t] + part[256 + t] + part[512 + t] + part[768 + t];
    xpT[((size_t)c << 10) + (n << 8) + t] = r * (1.f / 64.f);
}

// Kernel 2: fused 1x1 conv + BatchNorm. Block per output channel o (9 blocks),
// 1024 threads = 16 waves: thread t owns BN sample t (= n*256+bin).
// c-loop: scalar weight broadcast (s_load) x coalesced xpT row; unroll 8 for
// 8 independent loads in flight. BN stats block-local via shfl + LDS reduce.
__global__ __launch_bounds__(1024) void convbn_kernel(const float* __restrict__ xpT,
                                                      const float* __restrict__ wconv,
                                                      const float* __restrict__ gamma,
                                                      const float* __restrict__ beta,
                                                      float* __restrict__ w9) {
    int o = blockIdx.x;
    int t = threadIdx.x;          // sample 0..1023
    const float* wrow = wconv + o * 256;
    float acc = 0.f;
    #pragma unroll 8
    for (int c = 0; c < 256; ++c)
        acc += wrow[c] * xpT[(c << 10) + t];
    float sum = acc, sq = acc * acc;
    #pragma unroll
    for (int off = 32; off > 0; off >>= 1) {
        sum += __shfl_down(sum, off);
        sq  += __shfl_down(sq, off);
    }
    __shared__ float ls[32];
    __shared__ float sc[2];
    int w = t >> 6;
    if ((t & 63) == 0) { ls[w] = sum; ls[16 + w] = sq; }
    __syncthreads();
    if (t == 0) {
        float S = 0.f, Q = 0.f;
        #pragma unroll
        for (int i = 0; i < 16; ++i) { S += ls[i]; Q += ls[16 + i]; }
        float mu = S * (1.f / 1024.f);
        float var = Q * (1.f / 1024.f) - mu * mu;
        float scale = gamma[o] * rsqrtf(var + EPS_);
        sc[0] = scale;
        sc[1] = beta[o] - mu * scale;
    }
    __syncthreads();
    w9[t * 9 + o] = acc * sc[0] + sc[1];
}

// Kernel 3: depthwise 3x3 conv, per-(n,ch) dynamic 9-tap kernel, zero pad 1.
// Block per (n,ch,row-tile of 16). LDS tile 18 rows x 132 (16B-aligned row
// stride; col x at index x+1; halo cols zeroed). 2-row x 4-col micro-tile.
__global__ __launch_bounds__(256) void dwconv_kernel(const float* __restrict__ x,
                                                     const float* __restrict__ w9,
                                                     float* __restrict__ out) {
    int b = blockIdx.x;
    int plane = b >> 3;          // n*C + ch
    int rt = b & 7;
    int r0 = rt * 16;
    const float* xin = x + (size_t)plane * HW_;
    float* po = out + (size_t)plane * HW_;
    const float* wp = w9 + plane * 9;    // block-uniform -> scalar loads
    float w[9];
    #pragma unroll
    for (int i = 0; i < 9; ++i) w[i] = wp[i];

    __shared__ __align__(16) float lds[18 * 132];
    int t = threadIdx.x;
    if (t < 18) {                 // zero halo columns (col -1 and col 128)
        lds[t * 132] = 0.f;
        lds[t * 132 + 129] = 0.f;
    }
    #pragma unroll
    for (int i = 0; i < 3; ++i) {
        int vi = i * 256 + t;
        if (vi < 576) {
            int lr = vi >> 5;            // lds row 0..17
            int c4 = (vi & 31) << 2;     // col 0,4,...,124
            int gr = r0 - 1 + lr;        // global row
            float4 val = make_float4(0.f, 0.f, 0.f, 0.f);
            if (gr >= 0 && gr < H_) val = *(const float4*)&xin[gr * W_ + c4];
            float* d = &lds[lr * 132 + c4 + 1];
            d[0] = val.x; d[1] = val.y; d[2] = val.z; d[3] = val.w;
        }
    }
    __syncthreads();

    int mr = t >> 5;              // 0..7  -> out rows olr, olr+1
    int mc = t & 31;              // 0..31 -> out cols mc*4..mc*4+3
    int olr = mr * 2;
    int oc0 = mc * 4;
    float rowv[4][6];
    #pragma unroll
    for (int j = 0; j < 4; ++j) {
        const float* rp = &lds[(olr + j) * 132 + oc0];
        float4 a = *(const float4*)rp;    // 16B-aligned ds_read_b128
        rowv[j][0] = a.x; rowv[j][1] = a.y; rowv[j][2] = a.z; rowv[j][3] = a.w;
        rowv[j][4] = rp[4]; rowv[j][5] = rp[5];
    }
    #pragma unroll
    for (int rr = 0; rr < 2; ++rr) {
        float res[4];
        #pragma unroll
        for (int cc = 0; cc < 4; ++cc) {
            float s = 0.f;
            #pragma unroll
            for (int dy = 0; dy < 3; ++dy)
                #pragma unroll
                for (int dx = 0; dx < 3; ++dx)
                    s += w[dy * 3 + dx] * rowv[rr + dy][cc + dx];
            res[cc] = s;
        }
        *(float4*)&po[(r0 + olr + rr) * W_ + oc0] =
            make_float4(res[0], res[1], res[2], res[3]);
    }
}

extern "C" void kernel_launch(void* const* d_in, const int* in_sizes, int n_in,
                              void* d_out, int out_size, void* d_ws, size_t ws_size,
                              hipStream_t stream) {
    const float* x     = (const float*)d_in[0];
    const float* wconv = (const float*)d_in[1];
    const float* gamma = (const float*)d_in[2];
    const float* beta  = (const float*)d_in[3];
    float* out = (float*)d_out;

    float* xpT = (float*)d_ws;                  // C * N*BINS = 262144 floats
    float* w9  = xpT + C_ * N_ * BINS;          // N*BINS*OC  = 9216 floats

    pool_kernel  <<<N_ * C_,     256, 0, stream>>>(x, xpT);
    convbn_kernel<<<OC,         1024, 0, stream>>>(xpT, wconv, gamma, beta, w9);
    dwconv_kernel<<<N_ * C_ * 8, 256, 0, stream>>>(x, w9, out);
}

// Round 4
// 147.854 us; speedup vs baseline: 1.1002x; 1.0176x over previous
//
#include <hip/hip_runtime.h>

#define N_ 4
#define C_ 256
#define H_ 128
#define W_ 128
#define HW_ (H_*W_)
#define BINS 256      // 16x16 pooled positions
#define OC 9
#define EPS_ 1e-5f

// Kernel 1: 8x8 average pool, atomic-free. Block per (n,c), 256 threads,
// fully-coalesced float4 reads. shfl_xor collapses each wave's partials;
// output transposed: xpT[c][n*256+bin] so stage 2 reads coalesced.
__global__ __launch_bounds__(256) void pool_kernel(const float* __restrict__ x,
                                                   float* __restrict__ xpT) {
    int b = blockIdx.x;          // n*C + c
    int n = b >> 8, c = b & 255;
    const float4* xv = (const float4*)(x + (size_t)b * HW_);
    __shared__ float part[4 * 256];
    int t = threadIdx.x;
    int w = t >> 6, l = t & 63;
    int j = (l & 31) >> 1;       // col bin 0..15
    bool writer = (l < 32) && ((l & 1) == 0);
    #pragma unroll
    for (int k = 0; k < 16; ++k) {
        float4 v = xv[k * 256 + t];   // coalesced: flat pixel = k*1024 + 4t
        float s = v.x + v.y + v.z + v.w;
        s += __shfl_xor(s, 1);        // pair lanes -> 8 cols of one row
        s += __shfl_xor(s, 32);       // combine the wave's two rows
        if (writer) part[w * 256 + k * 16 + j] = s;
    }
    __syncthreads();
    float r = part[t] + part[256 + t] + part[512 + t] + part[768 + t];
    xpT[((size_t)c << 10) + (n << 8) + t] = r * (1.f / 64.f);
}

// Kernel 2: fused 1x1 conv + BatchNorm. Block per output channel o (9 blocks),
// 1024 threads = 16 waves: thread t owns BN sample t (= n*256+bin).
// unroll 16 -> 16 independent L2/L3 loads in flight per wave.
__global__ __launch_bounds__(1024) void convbn_kernel(const float* __restrict__ xpT,
                                                      const float* __restrict__ wconv,
                                                      const float* __restrict__ gamma,
                                                      const float* __restrict__ beta,
                                                      float* __restrict__ w9) {
    int o = blockIdx.x;
    int t = threadIdx.x;          // sample 0..1023
    const float* wrow = wconv + o * 256;
    float acc = 0.f;
    #pragma unroll 16
    for (int c = 0; c < 256; ++c)
        acc += wrow[c] * xpT[(c << 10) + t];
    float sum = acc, sq = acc * acc;
    #pragma unroll
    for (int off = 32; off > 0; off >>= 1) {
        sum += __shfl_down(sum, off);
        sq  += __shfl_down(sq, off);
    }
    __shared__ float ls[32];
    __shared__ float sc[2];
    int w = t >> 6;
    if ((t & 63) == 0) { ls[w] = sum; ls[16 + w] = sq; }
    __syncthreads();
    if (t == 0) {
        float S = 0.f, Q = 0.f;
        #pragma unroll
        for (int i = 0; i < 16; ++i) { S += ls[i]; Q += ls[16 + i]; }
        float mu = S * (1.f / 1024.f);
        float var = Q * (1.f / 1024.f) - mu * mu;
        float scale = gamma[o] * rsqrtf(var + EPS_);
        sc[0] = scale;
        sc[1] = beta[o] - mu * scale;
    }
    __syncthreads();
    w9[t * 9 + o] = acc * sc[0] + sc[1];
}

// Kernel 3: depthwise 3x3 conv, per-(n,ch) dynamic 9-tap kernel, zero pad 1.
// Block per (n,ch,row-tile of 32): halo overhead 34/32 = +6.25% (was +12.5%).
// LDS tile 34 rows x 132 (16B-aligned row stride; col x at index x+1; halo
// cols zeroed). Each thread computes a 4-row x 4-col micro-tile (16 outputs
// from 6 staged rows -> 1.125 LDS ops/output, was 1.5).
__global__ __launch_bounds__(256) void dwconv_kernel(const float* __restrict__ x,
                                                     const float* __restrict__ w9,
                                                     float* __restrict__ out) {
    int b = blockIdx.x;
    int plane = b >> 2;          // n*C + ch
    int rt = b & 3;
    int r0 = rt * 32;
    const float* xin = x + (size_t)plane * HW_;
    float* po = out + (size_t)plane * HW_;
    const float* wp = w9 + plane * 9;    // block-uniform -> scalar loads
    float w[9];
    #pragma unroll
    for (int i = 0; i < 9; ++i) w[i] = wp[i];

    __shared__ __align__(16) float lds[34 * 132];
    int t = threadIdx.x;
    if (t < 34) {                 // zero halo columns (col -1 and col 128)
        lds[t * 132] = 0.f;
        lds[t * 132 + 129] = 0.f;
    }
    // stage 34 rows x 128 cols = 1088 float4 loads, coalesced
    #pragma unroll
    for (int i = 0; i < 5; ++i) {
        int vi = i * 256 + t;
        if (vi < 1088) {
            int lr = vi >> 5;            // lds row 0..33
            int c4 = (vi & 31) << 2;     // col 0,4,...,124
            int gr = r0 - 1 + lr;        // global row
            float4 val = make_float4(0.f, 0.f, 0.f, 0.f);
            if (gr >= 0 && gr < H_) val = *(const float4*)&xin[gr * W_ + c4];
            float* d = &lds[lr * 132 + c4 + 1];
            d[0] = val.x; d[1] = val.y; d[2] = val.z; d[3] = val.w;
        }
    }
    __syncthreads();

    int mr = t >> 5;              // 0..7  -> out rows mr*4 .. mr*4+3
    int mc = t & 31;              // 0..31 -> out cols mc*4 .. mc*4+3
    int olr = mr * 4;
    int oc0 = mc * 4;
    // rowv[j][i] = input col (oc0 + i - 1) of lds row (olr + j), j=0..5
    float rowv[6][6];
    #pragma unroll
    for (int j = 0; j < 6; ++j) {
        const float* rp = &lds[(olr + j) * 132 + oc0];
        float4 a = *(const float4*)rp;    // 16B-aligned ds_read_b128
        rowv[j][0] = a.x; rowv[j][1] = a.y; rowv[j][2] = a.z; rowv[j][3] = a.w;
        rowv[j][4] = rp[4]; rowv[j][5] = rp[5];
    }
    #pragma unroll
    for (int rr = 0; rr < 4; ++rr) {
        float res[4];
        #pragma unroll
        for (int cc = 0; cc < 4; ++cc) {
            float s = 0.f;
            #pragma unroll
            for (int dy = 0; dy < 3; ++dy)
                #pragma unroll
                for (int dx = 0; dx < 3; ++dx)
                    s += w[dy * 3 + dx] * rowv[rr + dy][cc + dx];
            res[cc] = s;
        }
        *(float4*)&po[(r0 + olr + rr) * W_ + oc0] =
            make_float4(res[0], res[1], res[2], res[3]);
    }
}

extern "C" void kernel_launch(void* const* d_in, const int* in_sizes, int n_in,
                              void* d_out, int out_size, void* d_ws, size_t ws_size,
                              hipStream_t stream) {
    const float* x     = (const float*)d_in[0];
    const float* wconv = (const float*)d_in[1];
    const float* gamma = (const float*)d_in[2];
    const float* beta  = (const float*)d_in[3];
    float* out = (float*)d_out;

    float* xpT = (float*)d_ws;                  // C * N*BINS = 262144 floats
    float* w9  = xpT + C_ * N_ * BINS;          // N*BINS*OC  = 9216 floats

    pool_kernel  <<<N_ * C_,     256, 0, stream>>>(x, xpT);
    convbn_kernel<<<OC,         1024, 0, stream>>>(xpT, wconv, gamma, beta, w9);
    dwconv_kernel<<<N_ * C_ * 4, 256, 0, stream>>>(x, w9, out);
}